// Round 5
// baseline (1174.689 us; speedup 1.0000x reference)
//
#include <hip/hip_runtime.h>

typedef unsigned short u16;
typedef unsigned int u32;
typedef unsigned long long u64;

using bf16x8 = __attribute__((ext_vector_type(8))) short;
using f32x4  = __attribute__((ext_vector_type(4))) float;

#define VOCAB 50000
#define VEXT  50256
#define OUT_AT_OFF 20102400L  // 400*50256

__device__ __forceinline__ u16 f2b(float f) {
  u32 x = __float_as_uint(f);
  u32 r = (x + 0x7fffu + ((x >> 16) & 1u)) >> 16;  // RNE f32->bf16
  return (u16)r;
}

// system-scope (MALL-coherent, cache-bypass) helpers
__device__ __forceinline__ u64 sload64(const u64* p) {
  return __hip_atomic_load(p, __ATOMIC_RELAXED, __HIP_MEMORY_SCOPE_SYSTEM);
}
__device__ __forceinline__ void sstore64(u64* p, u64 v) {
  __hip_atomic_store(p, v, __ATOMIC_RELAXED, __HIP_MEMORY_SCOPE_SYSTEM);
}

// ---------------- generic f32 -> bf16 (with zero row padding at tail) ----------------
__global__ void k_conv(const float* __restrict__ src, u16* __restrict__ dst,
                       long realN, long totalN) {
  long i = (long)blockIdx.x * 256 + threadIdx.x;
  if (i >= totalN) return;
  float v = (i < realN) ? src[i] : 0.f;
  dst[i] = f2b(v);
}

// ---------------- h0 f32 [4][8][512] -> bf16 [4][16][512] (batch-padded) -------------
__global__ void k_h0b(const float* __restrict__ hidden, u16* __restrict__ h0B) {
  int i = blockIdx.x * 256 + threadIdx.x;  // < 4*16*512
  int l = i >> 13, rem = i & 8191, rr = rem >> 9, k = rem & 511;
  float v = (rr < 8) ? hidden[((long)l * 8 + rr) * 512 + k] : 0.f;
  h0B[i] = f2b(v);
}

// ---------------- embedding + g3 dot ----------------
__global__ __launch_bounds__(256) void k_prep(const int* __restrict__ tar,
                                              const float* __restrict__ emb,
                                              const float* __restrict__ g3w,
                                              u16* __restrict__ xB0,
                                              float* __restrict__ g3dot) {
  int r = blockIdx.x;  // b*50+t
  int tid = threadIdx.x;
  int idx = tar[r];
  __shared__ float red[256];
  float p = 0.f;
  for (int k = tid; k < 512; k += 256) {
    float v = (idx == 0) ? 0.f : emb[(long)idx * 512 + k];
    xB0[(long)r * 512 + k] = f2b(v);
    p += v * g3w[k];
  }
  red[tid] = p; __syncthreads();
  for (int o = 128; o > 0; o >>= 1) { if (tid < o) red[tid] += red[tid + o]; __syncthreads(); }
  if (tid == 0) g3dot[r] = red[0];
}

__global__ void k_lengths(const int* __restrict__ tar, int* __restrict__ lens) {
  int b = threadIdx.x;
  if (b < 8) {
    int c = 0;
    for (int t = 0; t < 50; t++) c += (tar[b * 50 + t] > 0) ? 1 : 0;
    lens[b] = (c > 0) ? c : 1;
  }
}

__global__ __launch_bounds__(256) void k_mask(float* __restrict__ x4f,
                                              const int* __restrict__ lens) {
  int r = blockIdx.x, b = r / 50, t = r % 50;
  if (t >= lens[b])
    for (int k = threadIdx.x; k < 512; k += 256) x4f[(long)r * 512 + k] = 0.f;
}

// ---------------- pipelined 4-layer GRU, bf16 MFMA ----------------------------------
// Sync protocol (v5, tagged dataflow): every cross-WG word is a 64-bit atomic
// (tag32 = step+1, payload32 = 2 bf16). Producer fires relaxed system stores (no
// drain, no flag, no RMW). Consumer loads the exact u64s it needs and retries until
// ALL tags match (the successful attempt already holds the data -> detection and
// data-load are ONE MALL round-trip). Tag-in-word makes partial visibility harmless.
// Double-buffer safety: WG X starts step t+1 only after reading all of h(t), which
// requires every peer to have published h(t), which happens after that peer finished
// reading h(t-1) -> no slot overwritten under a pending reader, tag==want suffices.
// Buffers zeroed each launch (stale tags from a previous replay alias current tags).
// Batch rows 8..15 are padding: never transported; consumer lanes use zeros.
__global__ __launch_bounds__(128, 1) void k_gru(
    const u16* __restrict__ wihB, const u16* __restrict__ whhB,
    const float* __restrict__ bih, const float* __restrict__ bhh,
    const float* __restrict__ hidden, const u16* __restrict__ h0B,
    const u16* __restrict__ xB0, // [16][50][512] bf16 layer-0 input (from k_prep)
    u64* __restrict__ hXT,   // [4][2][8][256] tagged u64 (h state, parity dbuf)
    u64* __restrict__ xT,    // [3][8][50][256] tagged u64 (inter-layer x handoff)
    float* __restrict__ x4f) // [8][50][512] f32 (layer-3 output, plain stores)
{
  const int wg = blockIdx.x;          // 0..127
  const int l = wg >> 5;              // layer
  const int c0 = (wg & 31) << 4;      // 16-col block of hidden dim
  const int tid = threadIdx.x;
  const int wv = tid >> 6;            // 0: gi wave, 1: gh wave
  const int lane = tid & 63;
  const int lrow = lane & 15;
  const int q = lane >> 4;

  __shared__ float giX[2][3][16][16];  // double-buffered by t&1

  // B fragments: 3 gate tiles x 16 k-steps, re-read per step (L1/L2-hot, no inv)
  const u16* Wsrc = (wv == 0 ? wihB : whhB) + (long)l * 1536 * 512;

  const int col = c0 + lrow;
  const float bir = bih[l * 1536 + col],         bhr = bhh[l * 1536 + col];
  const float biz = bih[l * 1536 + 512 + col],   bhz = bhh[l * 1536 + 512 + col];
  const float bin_ = bih[l * 1536 + 1024 + col], bhn = bhh[l * 1536 + 1024 + col];

  // hprev carried in registers: same lane owns (bb=q*4+rg, col) every step
  float hreg[4];
  if (wv == 1) {
#pragma unroll
    for (int rg = 0; rg < 4; rg++) {
      int bb = q * 4 + rg;
      hreg[rg] = (bb < 8) ? hidden[((long)l * 8 + bb) * 512 + col] : 0.f;
    }
  }

  for (int t = 0; t < 50; t++) {
    bf16x8 af[16];
    bool plain = (wv == 0) ? (l == 0) : (t == 0);
    if (plain) {
      const u16* Asrc = (wv == 0) ? (xB0 + (long)lrow * 50 * 512 + (long)t * 512)
                                  : (h0B + ((long)l * 16 + lrow) * 512);
#pragma unroll
      for (int ks = 0; ks < 16; ks++) af[ks] = *(const bf16x8*)(Asrc + ks * 32 + q * 8);
    } else {
      // tagged dataflow load: retry until all 64 tags match (rows 0..7 only)
      const u64* S;
      u32 want;
      if (wv == 0) { S = xT + ((((long)(l - 1) * 8 + lrow) * 50) + t) * 256; want = (u32)(t + 1); }
      else         { S = hXT + (((long)l * 2 + ((t - 1) & 1)) * 8 + lrow) * 256; want = (u32)t; }
      union { u32 w[4]; bf16x8 v; } fr[16];
      unsigned it = 0;
      while (true) {
        bool okl = true;
        if (lrow < 8) {
#pragma unroll
          for (int ks = 0; ks < 16; ks++) {
#pragma unroll
            for (int j = 0; j < 4; j++) {
              u64 tv = sload64(S + ks * 16 + q * 4 + j);
              okl &= ((u32)(tv >> 32) == want);
              fr[ks].w[j] = (u32)tv;
            }
          }
        }
        if (__all((int)okl)) break;
        __builtin_amdgcn_s_sleep(1);
        if (++it > (1u << 20)) break;  // safety: wrong-but-terminating on logic bug
      }
      if (lrow < 8) {
#pragma unroll
        for (int ks = 0; ks < 16; ks++) af[ks] = fr[ks].v;
      } else {
#pragma unroll
        for (int ks = 0; ks < 16; ks++) af[ks] = bf16x8{0, 0, 0, 0, 0, 0, 0, 0};
      }
    }

    f32x4 a0 = {0.f, 0.f, 0.f, 0.f}, a1 = {0.f, 0.f, 0.f, 0.f}, a2 = {0.f, 0.f, 0.f, 0.f};
#pragma unroll
    for (int ks = 0; ks < 16; ks++) {
      bf16x8 b0 = *(const bf16x8*)(Wsrc + (long)(0 * 512 + c0 + lrow) * 512 + ks * 32 + q * 8);
      bf16x8 b1 = *(const bf16x8*)(Wsrc + (long)(1 * 512 + c0 + lrow) * 512 + ks * 32 + q * 8);
      bf16x8 b2 = *(const bf16x8*)(Wsrc + (long)(2 * 512 + c0 + lrow) * 512 + ks * 32 + q * 8);
      a0 = __builtin_amdgcn_mfma_f32_16x16x32_bf16(af[ks], b0, a0, 0, 0, 0);
      a1 = __builtin_amdgcn_mfma_f32_16x16x32_bf16(af[ks], b1, a1, 0, 0, 0);
      a2 = __builtin_amdgcn_mfma_f32_16x16x32_bf16(af[ks], b2, a2, 0, 0, 0);
    }

    if (wv == 0) {
#pragma unroll
      for (int rg = 0; rg < 4; rg++) {
        giX[t & 1][0][q * 4 + rg][lrow] = a0[rg];
        giX[t & 1][1][q * 4 + rg][lrow] = a1[rg];
        giX[t & 1][2][q * 4 + rg][lrow] = a2[rg];
      }
    }
    __syncthreads();

    if (wv == 1) {
#pragma unroll
      for (int rg = 0; rg < 4; rg++) {
        int bb = q * 4 + rg;
        float hnew = 0.f;
        u16 hb16 = 0;
        if (bb < 8) {
          float gir = giX[t & 1][0][bb][lrow] + bir;
          float giz = giX[t & 1][1][bb][lrow] + biz;
          float gin = giX[t & 1][2][bb][lrow] + bin_;
          float ghr = a0[rg] + bhr;
          float ghz = a1[rg] + bhz;
          float ghn = a2[rg] + bhn;
          float hprev = hreg[rg];
          float rr = 1.f / (1.f + expf(-(gir + ghr)));
          float zz = 1.f / (1.f + expf(-(giz + ghz)));
          float nn = tanhf(gin + rr * ghn);
          hnew = (1.f - zz) * nn + zz * hprev;
          hreg[rg] = hnew;
          hb16 = f2b(hnew);
        }
        // pack (col, col+1) across adjacent lanes; tag in high 32 bits
        u32 p32 = (u32)hb16 | ((u32)(u16)__shfl_xor((int)hb16, 1) << 16);
        if (bb < 8) {
          if ((lane & 1) == 0) {
            u64 tv = ((u64)(u32)(t + 1) << 32) | (u64)p32;
            sstore64(hXT + (((long)l * 2 + (t & 1)) * 8 + bb) * 256 + ((c0 + lrow) >> 1), tv);
            if (l < 3)
              sstore64(xT + ((((long)l * 8 + bb) * 50) + t) * 256 + ((c0 + lrow) >> 1), tv);
          }
          if (l == 3) x4f[((long)bb * 50 + t) * 512 + col] = hnew;
        }
      }
      // no drain, no flag: the tagged stores ARE the publication
    }
  }
}

// ---------------- generic bf16 MFMA GEMM: C[M,N] = A[Mp,K] @ Bm[Np,K]^T + bias ------
__global__ __launch_bounds__(256, 2) void k_gemm_bf16(
    const u16* __restrict__ A, const u16* __restrict__ Bm,
    const float* __restrict__ bias, float* __restrict__ C,
    int M, int N, int K, int ldc)
{
  __shared__ __align__(16) u16 As[4096];
  __shared__ __align__(16) u16 Bs[4096];
  const int tid = threadIdx.x;
  const int wv = tid >> 6, lane = tid & 63;
  const int wm = wv >> 1, wn = wv & 1;
  const int lrow = lane & 15, q = lane >> 4;
  const int m0 = blockIdx.y * 128, n0 = blockIdx.x * 128;

  f32x4 acc[4][4];
#pragma unroll
  for (int i = 0; i < 4; i++)
#pragma unroll
    for (int j = 0; j < 4; j++) acc[i][j] = {0.f, 0.f, 0.f, 0.f};

  for (int k0 = 0; k0 < K; k0 += 32) {
#pragma unroll
    for (int i = 0; i < 2; i++) {
      int c = i * 256 + tid;
      int row = c >> 2, ko = (c & 3) << 3;
      *(uint4*)(As + c * 8) = *(const uint4*)(A + (long)(m0 + row) * K + k0 + ko);
      *(uint4*)(Bs + c * 8) = *(const uint4*)(Bm + (long)(n0 + row) * K + k0 + ko);
    }
    __syncthreads();
    bf16x8 af[4], bfr[4];
#pragma unroll
    for (int i = 0; i < 4; i++) af[i] = *(const bf16x8*)(As + (wm * 64 + i * 16 + lrow) * 32 + q * 8);
#pragma unroll
    for (int j = 0; j < 4; j++) bfr[j] = *(const bf16x8*)(Bs + (wn * 64 + j * 16 + lrow) * 32 + q * 8);
#pragma unroll
    for (int i = 0; i < 4; i++)
#pragma unroll
      for (int j = 0; j < 4; j++)
        acc[i][j] = __builtin_amdgcn_mfma_f32_16x16x32_bf16(af[i], bfr[j], acc[i][j], 0, 0, 0);
    __syncthreads();
  }

#pragma unroll
  for (int i = 0; i < 4; i++) {
    int rbase = m0 + wm * 64 + i * 16 + q * 4;
#pragma unroll
    for (int j = 0; j < 4; j++) {
      int colg = n0 + wn * 64 + j * 16 + lrow;
      if (colg < N) {
        float bv = bias[colg];
#pragma unroll
        for (int rg = 0; rg < 4; rg++) {
          int rowg = rbase + rg;
          if (rowg < M) C[(long)rowg * ldc + colg] = acc[i][j][rg] + bv;
        }
      }
    }
  }
}

// ---------------- attention: scores + softmax + weighted + gate ----------------
__global__ __launch_bounds__(256) void k_attn(
    const float* __restrict__ e1, const float* __restrict__ e2,
    const float* __restrict__ enc, const float* __restrict__ x4f,
    const int* __restrict__ sou, const float* __restrict__ vw,
    const float* __restrict__ g1w, const float* __restrict__ g1b,
    const float* __restrict__ g2w, const float* __restrict__ g2b,
    const float* __restrict__ g3b, const float* __restrict__ g3dot,
    float* __restrict__ all_out, float* __restrict__ gate,
    float* __restrict__ atten_out)
{
  int r = blockIdx.x;  // b*50+t
  int b = r / 50;
  int tid = threadIdx.x;  // = s
  __shared__ float e2s[512], decs[512], at[256], red[256];
  for (int k = tid; k < 512; k += 256) {
    e2s[k] = e2[(long)r * 512 + k];
    decs[k] = x4f[(long)r * 512 + k];
  }
  __syncthreads();
  const float* erow = e1 + ((long)b * 256 + tid) * 512;
  float sc = 0.f;
#pragma unroll 4
  for (int h = 0; h < 512; h++) sc += vw[h] * tanhf(erow[h] + e2s[h]);
  if (sou[b * 256 + tid] == 0) sc = -INFINITY;

  red[tid] = sc; __syncthreads();
  for (int o = 128; o > 0; o >>= 1) { if (tid < o) red[tid] = fmaxf(red[tid], red[tid + o]); __syncthreads(); }
  float mx = red[0]; __syncthreads();
  float p = expf(sc - mx);
  red[tid] = p; __syncthreads();
  for (int o = 128; o > 0; o >>= 1) { if (tid < o) red[tid] += red[tid + o]; __syncthreads(); }
  float S = red[0]; __syncthreads();
  float a = p / S;
  at[tid] = a;
  atten_out[(long)r * 256 + tid] = a;
  __syncthreads();

  float pg = 0.f;
  for (int h = tid; h < 512; h += 256) {
    float wsum = 0.f;
    const float* ecol = enc + (long)b * 256 * 512 + h;
    for (int s = 0; s < 256; s++) wsum += at[s] * ecol[(long)s * 512];
    all_out[(long)r * 1024 + h] = wsum;
    all_out[(long)r * 1024 + 512 + h] = decs[h];
    pg += wsum * g1w[h] + decs[h] * g2w[h];
  }
  red[tid] = pg; __syncthreads();
  for (int o = 128; o > 0; o >>= 1) { if (tid < o) red[tid] += red[tid + o]; __syncthreads(); }
  if (tid == 0) {
    float z = red[0] + g1b[0] + g2b[0] + g3dot[r] + g3b[0];
    gate[r] = 1.f / (1.f + expf(-z));
  }
}

// ---------------- in-place masked softmax * (1-gate) over d_out logits -------------
__global__ __launch_bounds__(1024) void k_softmax(float* __restrict__ out,
                                                  const float* __restrict__ gate,
                                                  const int* __restrict__ ext) {
  int r = blockIdx.x;
  int b = r / 50;
  int tid = threadIdx.x;
  int nv = VOCAB + ext[b];
  __shared__ float red[1024];
  float* row = out + (long)r * VEXT;
  float m = -INFINITY;
  for (int c = tid; c < nv; c += 1024) m = fmaxf(m, row[c]);
  red[tid] = m; __syncthreads();
  for (int o = 512; o > 0; o >>= 1) { if (tid < o) red[tid] = fmaxf(red[tid], red[tid + o]); __syncthreads(); }
  m = red[0]; __syncthreads();
  float s = 0.f;
  for (int c = tid; c < nv; c += 1024) s += expf(row[c] - m);
  red[tid] = s; __syncthreads();
  for (int o = 512; o > 0; o >>= 1) { if (tid < o) red[tid] += red[tid + o]; __syncthreads(); }
  float inv = (1.f - gate[r]) / red[0];
  for (int c = tid; c < VEXT; c += 1024) {
    float v = (c < nv) ? expf(row[c] - m) * inv : 0.f;
    row[c] = v;
  }
}

// ---------------- copy mechanism scatter ----------------
__global__ void k_scatter(float* __restrict__ out, const float* __restrict__ atten,
                          const float* __restrict__ gate, const int* __restrict__ sou) {
  int r = blockIdx.x, s = threadIdx.x;
  int b = r / 50;
  float v = gate[r] * atten[(long)r * 256 + s];
  int colv = sou[b * 256 + s];
  atomicAdd(out + (long)r * VEXT + colv, v);
}

extern "C" void kernel_launch(void* const* d_in, const int* in_sizes, int n_in,
                              void* d_out, int out_size, void* d_ws, size_t ws_size,
                              hipStream_t stream) {
  (void)in_sizes; (void)n_in; (void)out_size;
  const int* sou = (const int*)d_in[0];
  const int* tar = (const int*)d_in[1];
  const float* hidden = (const float*)d_in[2];
  const float* enc = (const float*)d_in[3];
  const int* ext = (const int*)d_in[4];
  const float* emb = (const float*)d_in[5];
  const float* wih = (const float*)d_in[6];
  const float* whh = (const float*)d_in[7];
  const float* bih = (const float*)d_in[8];
  const float* bhh = (const float*)d_in[9];
  const float* fc_enc_w = (const float*)d_in[10];
  const float* fc_enc_b = (const float*)d_in[11];
  const float* fc_dec_w = (const float*)d_in[12];
  const float* fc_dec_b = (const float*)d_in[13];
  const float* v_w = (const float*)d_in[14];
  const float* w1 = (const float*)d_in[15];
  const float* b1 = (const float*)d_in[16];
  const float* w2 = (const float*)d_in[17];
  const float* b2 = (const float*)d_in[18];
  const float* g1w = (const float*)d_in[19];
  const float* g1b = (const float*)d_in[20];
  const float* g2w = (const float*)d_in[21];
  const float* g2b = (const float*)d_in[22];
  const float* g3w = (const float*)d_in[23];
  const float* g3b = (const float*)d_in[24];
  float* out = (float*)d_out;

  char* base = (char*)d_ws;
  size_t cur = 0;
  auto alloc = [&](size_t bytes) -> void* {
    void* r = base + cur;
    cur = (cur + bytes + 255) & ~(size_t)255;
    return r;
  };
  u16* wihB = (u16*)alloc(6291456);     // [4][1536][512] bf16
  u16* whhB = (u16*)alloc(6291456);
  u16* w1B  = (u16*)alloc(51511296);    // [50304][512] bf16 (padded)
  u16* encB = (u16*)alloc(2097152);     // [2048][512]
  u16* fceB = (u16*)alloc(524288);      // [512][512]
  u16* fcdB = (u16*)alloc(524288);
  u16* fo2B = (u16*)alloc(1048576);     // [512][1024]
  u16* midB = (u16*)alloc(524288);      // [512][512] (400 real)
  u16* decB = (u16*)alloc(524288);
  u16* allB = (u16*)alloc(1048576);     // [512][1024]
  u16* xB0  = (u16*)alloc(819200);      // [16][50][512] bf16 layer-0 input
  u16* h0B  = (u16*)alloc(65536);       // [4][16][512]
  u64* hXT  = (u64*)alloc(131072);      // [4][2][8][256] tagged u64
  u64* xT   = (u64*)alloc(2457600);     // [3][8][50][256] tagged u64
  float* x4f = (float*)alloc(819200);   // [400][512]
  float* e1 = (float*)alloc(4194304);   // [2048][512]
  float* e2 = (float*)alloc(819200);    // [400][512]
  float* allo = (float*)alloc(1638400); // [400][1024]
  float* mid = (float*)alloc(819200);   // [400][512]
  float* g3dot = (float*)alloc(1600);
  float* gate = (float*)alloc(1600);
  int* lens = (int*)alloc(32);
  if (cur > ws_size) return;  // ws too small -> loud failure, recognizable vs stub

  // zero tags (hXT and xT are adjacent; stale tags would alias current ones)
  hipMemsetAsync(hXT, 0, 131072 + 2457600, stream);

  // weight / input conversions to bf16
  k_conv<<<12288, 256, 0, stream>>>(wih, wihB, 3145728L, 3145728L);
  k_conv<<<12288, 256, 0, stream>>>(whh, whhB, 3145728L, 3145728L);
  k_conv<<<100608, 256, 0, stream>>>(w1, w1B, 25731072L, 25755648L);
  k_conv<<<4096, 256, 0, stream>>>(enc, encB, 1048576L, 1048576L);
  k_conv<<<1024, 256, 0, stream>>>(fc_enc_w, fceB, 262144L, 262144L);
  k_conv<<<1024, 256, 0, stream>>>(fc_dec_w, fcdB, 262144L, 262144L);
  k_conv<<<2048, 256, 0, stream>>>(w2, fo2B, 524288L, 524288L);
  k_h0b<<<128, 256, 0, stream>>>(hidden, h0B);
  k_prep<<<400, 256, 0, stream>>>(tar, emb, g3w, xB0, g3dot);
  k_lengths<<<1, 64, 0, stream>>>(tar, lens);

  // pipelined GRU (all 4 layers, tagged-dataflow sync)
  k_gru<<<128, 128, 0, stream>>>(wihB, whhB, bih, bhh, hidden, h0B, xB0, hXT, xT, x4f);
  k_mask<<<400, 256, 0, stream>>>(x4f, lens);
  k_conv<<<1024, 256, 0, stream>>>(x4f, decB, 204800L, 262144L);

  // attention path
  k_gemm_bf16<<<dim3(4, 16), 256, 0, stream>>>(encB, fceB, fc_enc_b, e1, 2048, 512, 512, 512);
  k_gemm_bf16<<<dim3(4, 4), 256, 0, stream>>>(decB, fcdB, fc_dec_b, e2, 400, 512, 512, 512);
  k_attn<<<400, 256, 0, stream>>>(e1, e2, enc, x4f, sou, v_w, g1w, g1b, g2w, g2b, g3b,
                                  g3dot, allo, gate, out + OUT_AT_OFF);
  k_conv<<<2048, 256, 0, stream>>>(allo, allB, 409600L, 524288L);
  k_gemm_bf16<<<dim3(4, 4), 256, 0, stream>>>(allB, fo2B, b2, mid, 400, 512, 1024, 512);
  k_conv<<<1024, 256, 0, stream>>>(mid, midB, 204800L, 262144L);

  // logits -> softmax -> copy scatter
  k_gemm_bf16<<<dim3(393, 4), 256, 0, stream>>>(midB, w1B, b1, out, 400, 50256, 512, 50256);
  k_softmax<<<400, 1024, 0, stream>>>(out, gate, ext);
  k_scatter<<<400, 256, 0, stream>>>(out, out + OUT_AT_OFF, gate, sou);
}

// Round 7
// 1038.229 us; speedup vs baseline: 1.1314x; 1.1314x over previous
//
#include <hip/hip_runtime.h>

typedef unsigned short u16;
typedef unsigned int u32;
typedef unsigned long long u64;

using bf16x8 = __attribute__((ext_vector_type(8))) short;
using f32x4  = __attribute__((ext_vector_type(4))) float;

#define VOCAB 50000
#define VEXT  50256
#define OUT_AT_OFF 20102400L  // 400*50256

__device__ __forceinline__ u16 f2b(float f) {
  u32 x = __float_as_uint(f);
  u32 r = (x + 0x7fffu + ((x >> 16) & 1u)) >> 16;  // RNE f32->bf16
  return (u16)r;
}

// system-scope (MALL-coherent, cache-bypass) helpers: fence-free protocol
__device__ __forceinline__ u32 sload32(const u32* p) {
  return __hip_atomic_load(p, __ATOMIC_RELAXED, __HIP_MEMORY_SCOPE_SYSTEM);
}
__device__ __forceinline__ u64 sload64(const u64* p) {
  return __hip_atomic_load(p, __ATOMIC_RELAXED, __HIP_MEMORY_SCOPE_SYSTEM);
}
__device__ __forceinline__ void sstore64(u64* p, u64 v) {
  __hip_atomic_store(p, v, __ATOMIC_RELAXED, __HIP_MEMORY_SCOPE_SYSTEM);
}
__device__ __forceinline__ bf16x8 sload8x(const u64* p) {
  union { u64 u[2]; bf16x8 v; } x;
  x.u[0] = sload64(p); x.u[1] = sload64(p + 1);
  return x.v;
}
// 4-way split counters: lanes poll 4 lines (lane&3), 4 transactions/wave/iter
__device__ __forceinline__ void wait_cnt4(const u32* c4, u32 tgt) {
  const u32* p = c4 + (threadIdx.x & 3) * 16;
  unsigned it = 0;
  while (true) {
    u32 v = sload32(p);
    if (__all((int)(v >= tgt))) break;
    __builtin_amdgcn_s_sleep(2);
    if (++it > (1u << 20)) break;  // safety: wrong-but-terminating on logic bug
  }
  asm volatile("" ::: "memory");  // compiler-only barrier (no cache op)
}

// ---------------- generic f32 -> bf16 (with zero row padding at tail) ----------------
__global__ void k_conv(const float* __restrict__ src, u16* __restrict__ dst,
                       long realN, long totalN) {
  long i = (long)blockIdx.x * 256 + threadIdx.x;
  if (i >= totalN) return;
  float v = (i < realN) ? src[i] : 0.f;
  dst[i] = f2b(v);
}

// ---------------- h0 f32 [4][8][512] -> bf16 [4][16][512] (batch-padded) -------------
__global__ void k_h0b(const float* __restrict__ hidden, u16* __restrict__ h0B) {
  int i = blockIdx.x * 256 + threadIdx.x;  // < 4*16*512
  int l = i >> 13, rem = i & 8191, rr = rem >> 9, k = rem & 511;
  float v = (rr < 8) ? hidden[((long)l * 8 + rr) * 512 + k] : 0.f;
  h0B[i] = f2b(v);
}

// ---------------- embedding + g3 dot ----------------
__global__ __launch_bounds__(256) void k_prep(const int* __restrict__ tar,
                                              const float* __restrict__ emb,
                                              const float* __restrict__ g3w,
                                              u16* __restrict__ xB0,
                                              float* __restrict__ g3dot) {
  int r = blockIdx.x;  // b*50+t
  int tid = threadIdx.x;
  int idx = tar[r];
  __shared__ float red[256];
  float p = 0.f;
  for (int k = tid; k < 512; k += 256) {
    float v = (idx == 0) ? 0.f : emb[(long)idx * 512 + k];
    xB0[(long)r * 512 + k] = f2b(v);
    p += v * g3w[k];
  }
  red[tid] = p; __syncthreads();
  for (int o = 128; o > 0; o >>= 1) { if (tid < o) red[tid] += red[tid + o]; __syncthreads(); }
  if (tid == 0) g3dot[r] = red[0];
}

__global__ void k_lengths(const int* __restrict__ tar, int* __restrict__ lens) {
  int b = threadIdx.x;
  if (b < 8) {
    int c = 0;
    for (int t = 0; t < 50; t++) c += (tar[b * 50 + t] > 0) ? 1 : 0;
    lens[b] = (c > 0) ? c : 1;
  }
}

__global__ __launch_bounds__(256) void k_mask(float* __restrict__ x4f,
                                              const int* __restrict__ lens) {
  int r = blockIdx.x, b = r / 50, t = r % 50;
  if (t >= lens[b])
    for (int k = threadIdx.x; k < 512; k += 256) x4f[(long)r * 512 + k] = 0.f;
}

// ---------------- pipelined 4-layer GRU, bf16 MFMA ----------------------------------
// Sync protocol (v6 = v4 + 4-way split counters + folded w1 conversion):
//  - per layer, 4 group-counters (8 WGs each) on separate 64B lines; producer does 1
//    memory-side relaxed system atomicAdd per step to its group line. Consumers poll
//    4 lines with 4 lanes (4 transactions/wave/iter). All-groups >= 8t <=> layer
//    finished step t-1 (lockstep proof as before).
//  - cross-WG data via relaxed system u64 atomics (bypass L1/L2); release =
//    s_waitcnt vmcnt(0) + relaxed add. No wbl2/inv anywhere -> weights L1/L2-hot.
//  - WGs 128..255 convert w1 f32->bf16 (grid-stride), overlapping the latency-bound
//    GRU pipeline with the 155 MB stream that otherwise serializes on-stream.
__global__ __launch_bounds__(128, 1) void k_gru(
    const u16* __restrict__ wihB, const u16* __restrict__ whhB,
    const float* __restrict__ bih, const float* __restrict__ bhh,
    const float* __restrict__ hidden, const u16* __restrict__ h0B,
    u16* __restrict__ xB,    // [4][16][50][512] bf16; xB[0] rows 0-7 from k_prep
    u32* __restrict__ hX,    // [4][2][16][256] u32 (bf16 col-pairs, parity dbuf)
    float* __restrict__ x4f, // [8][50][512] f32 (layer-3 output, plain stores)
    u32* __restrict__ cnt,   // [4][4][16] u32: 4 group-counters per layer
    const float* __restrict__ w1src, u16* __restrict__ w1B)
{
  const int wg = blockIdx.x;          // 0..255
  const int tid = threadIdx.x;

  if (wg >= 128) {
    // ---- folded w1 conversion: [50304][512] bf16, zero-padded past 25731072 ----
    long tidg = (long)(wg - 128) * 128 + tid;  // 0..16383
    const float4* src4 = (const float4*)w1src;
#pragma unroll 4
    for (int it = 0; it < 393; it++) {
      long e = tidg * 4 + (long)it * 65536;    // quad-aligned element index
      float4 v = {0.f, 0.f, 0.f, 0.f};
      if (e < 25731072L) v = src4[e >> 2];
      u64 o = (u64)f2b(v.x) | ((u64)f2b(v.y) << 16) |
              ((u64)f2b(v.z) << 32) | ((u64)f2b(v.w) << 48);
      *(u64*)(w1B + e) = o;
    }
    return;
  }

  const int l = wg >> 5;              // layer
  const int wg32 = wg & 31;
  const int c0 = wg32 << 4;           // 16-col block of hidden dim
  const int wv = tid >> 6;            // 0: gi wave, 1: gh wave
  const int lane = tid & 63;
  const int lrow = lane & 15;
  const int q = lane >> 4;

  __shared__ float giX[2][3][16][16];  // double-buffered by t&1

  // B fragments: 3 gate tiles x 16 k-steps, re-read per step (L1/L2-hot, no inv)
  const u16* Wsrc = (wv == 0 ? wihB : whhB) + (long)l * 1536 * 512;

  const int col = c0 + lrow;
  const float bir = bih[l * 1536 + col],         bhr = bhh[l * 1536 + col];
  const float biz = bih[l * 1536 + 512 + col],   bhz = bhh[l * 1536 + 512 + col];
  const float bin_ = bih[l * 1536 + 1024 + col], bhn = bhh[l * 1536 + 1024 + col];

  const u16* xin = xB + (long)l * 16 * 50 * 512;

  // hprev carried in registers: same lane owns (bb=q*4+rg, col) every step
  float hreg[4];
  if (wv == 1) {
#pragma unroll
    for (int rg = 0; rg < 4; rg++) {
      int bb = q * 4 + rg;
      hreg[rg] = (bb < 8) ? hidden[((long)l * 8 + bb) * 512 + col] : 0.f;
    }
  }

  for (int t = 0; t < 50; t++) {
    bf16x8 af[16];
    if (wv == 0) {
      if (l > 0) {
        wait_cnt4(cnt + (l - 1) * 64, 8u * (u32)(t + 1));  // layer l-1 finished step t
        const u64* A64 = (const u64*)((const u32*)xin + (long)lrow * 50 * 256 + (long)t * 256);
#pragma unroll
        for (int ks = 0; ks < 16; ks++) af[ks] = sload8x(A64 + ks * 8 + q * 2);
      } else {
        const u16* Asrc = xin + (long)lrow * 50 * 512 + (long)t * 512;
#pragma unroll
        for (int ks = 0; ks < 16; ks++) af[ks] = *(const bf16x8*)(Asrc + ks * 32 + q * 8);
      }
    } else {
      if (t > 0) {
        wait_cnt4(cnt + l * 64, 8u * (u32)t);              // own layer finished step t-1
        const u64* H64 = (const u64*)(hX + (((long)l * 2 + ((t - 1) & 1)) * 16 + lrow) * 256);
#pragma unroll
        for (int ks = 0; ks < 16; ks++) af[ks] = sload8x(H64 + ks * 8 + q * 2);
      } else {
        const u16* Asrc = h0B + ((long)l * 16 + lrow) * 512;
#pragma unroll
        for (int ks = 0; ks < 16; ks++) af[ks] = *(const bf16x8*)(Asrc + ks * 32 + q * 8);
      }
    }

    f32x4 a0 = {0.f, 0.f, 0.f, 0.f}, a1 = {0.f, 0.f, 0.f, 0.f}, a2 = {0.f, 0.f, 0.f, 0.f};
#pragma unroll
    for (int ks = 0; ks < 16; ks++) {
      bf16x8 b0 = *(const bf16x8*)(Wsrc + (long)(0 * 512 + c0 + lrow) * 512 + ks * 32 + q * 8);
      bf16x8 b1 = *(const bf16x8*)(Wsrc + (long)(1 * 512 + c0 + lrow) * 512 + ks * 32 + q * 8);
      bf16x8 b2 = *(const bf16x8*)(Wsrc + (long)(2 * 512 + c0 + lrow) * 512 + ks * 32 + q * 8);
      a0 = __builtin_amdgcn_mfma_f32_16x16x32_bf16(af[ks], b0, a0, 0, 0, 0);
      a1 = __builtin_amdgcn_mfma_f32_16x16x32_bf16(af[ks], b1, a1, 0, 0, 0);
      a2 = __builtin_amdgcn_mfma_f32_16x16x32_bf16(af[ks], b2, a2, 0, 0, 0);
    }

    if (wv == 0) {
#pragma unroll
      for (int rg = 0; rg < 4; rg++) {
        giX[t & 1][0][q * 4 + rg][lrow] = a0[rg];
        giX[t & 1][1][q * 4 + rg][lrow] = a1[rg];
        giX[t & 1][2][q * 4 + rg][lrow] = a2[rg];
      }
    }
    __syncthreads();

    if (wv == 1) {
#pragma unroll
      for (int rg = 0; rg < 4; rg++) {
        int bb = q * 4 + rg;
        float hnew = 0.f;
        u16 hb16 = 0;
        if (bb < 8) {
          float gir = giX[t & 1][0][bb][lrow] + bir;
          float giz = giX[t & 1][1][bb][lrow] + biz;
          float gin = giX[t & 1][2][bb][lrow] + bin_;
          float ghr = a0[rg] + bhr;
          float ghz = a1[rg] + bhz;
          float ghn = a2[rg] + bhn;
          float hprev = hreg[rg];
          float rr = 1.f / (1.f + expf(-(gir + ghr)));
          float zz = 1.f / (1.f + expf(-(giz + ghz)));
          float nn = tanhf(gin + rr * ghn);
          hnew = (1.f - zz) * nn + zz * hprev;
          hreg[rg] = hnew;
          hb16 = f2b(hnew);
        }
        // pack 4 consecutive cols into one u64 (2 shfl_xor rounds, wave-uniform)
        u32 p32 = (u32)hb16 | ((u32)(u16)__shfl_xor((int)hb16, 1) << 16);
        u64 p64 = (u64)p32 | ((u64)(u32)__shfl_xor((int)p32, 2) << 32);
        if (bb < 8) {
          if ((lrow & 3) == 0) {
            long slot = ((long)l * 2 + (t & 1)) * 16 + bb;
            sstore64((u64*)hX + slot * 128 + (col >> 2), p64);
            if (l < 3)
              sstore64((u64*)xB + ((((long)(l + 1) * 16 + bb) * 50 + t) * 128) + (col >> 2), p64);
          }
          if (l == 3) x4f[((long)bb * 50 + t) * 512 + col] = hnew;
        }
      }
      // release: drain this wave's stores to the coherence point, then publish
      asm volatile("s_waitcnt vmcnt(0)" ::: "memory");
      if (lane == 0)
        __hip_atomic_fetch_add(cnt + (long)l * 64 + (wg32 >> 3) * 16, 1u,
                               __ATOMIC_RELAXED, __HIP_MEMORY_SCOPE_SYSTEM);
    }
  }
}

// ---------------- generic bf16 MFMA GEMM: C[M,N] = A[Mp,K] @ Bm[Np,K]^T + bias ------
__global__ __launch_bounds__(256, 2) void k_gemm_bf16(
    const u16* __restrict__ A, const u16* __restrict__ Bm,
    const float* __restrict__ bias, float* __restrict__ C,
    int M, int N, int K, int ldc)
{
  __shared__ __align__(16) u16 As[4096];
  __shared__ __align__(16) u16 Bs[4096];
  const int tid = threadIdx.x;
  const int wv = tid >> 6, lane = tid & 63;
  const int wm = wv >> 1, wn = wv & 1;
  const int lrow = lane & 15, q = lane >> 4;
  const int m0 = blockIdx.y * 128, n0 = blockIdx.x * 128;

  f32x4 acc[4][4];
#pragma unroll
  for (int i = 0; i < 4; i++)
#pragma unroll
    for (int j = 0; j < 4; j++) acc[i][j] = {0.f, 0.f, 0.f, 0.f};

  for (int k0 = 0; k0 < K; k0 += 32) {
#pragma unroll
    for (int i = 0; i < 2; i++) {
      int c = i * 256 + tid;
      int row = c >> 2, ko = (c & 3) << 3;
      *(uint4*)(As + c * 8) = *(const uint4*)(A + (long)(m0 + row) * K + k0 + ko);
      *(uint4*)(Bs + c * 8) = *(const uint4*)(Bm + (long)(n0 + row) * K + k0 + ko);
    }
    __syncthreads();
    bf16x8 af[4], bfr[4];
#pragma unroll
    for (int i = 0; i < 4; i++) af[i] = *(const bf16x8*)(As + (wm * 64 + i * 16 + lrow) * 32 + q * 8);
#pragma unroll
    for (int j = 0; j < 4; j++) bfr[j] = *(const bf16x8*)(Bs + (wn * 64 + j * 16 + lrow) * 32 + q * 8);
#pragma unroll
    for (int i = 0; i < 4; i++)
#pragma unroll
      for (int j = 0; j < 4; j++)
        acc[i][j] = __builtin_amdgcn_mfma_f32_16x16x32_bf16(af[i], bfr[j], acc[i][j], 0, 0, 0);
    __syncthreads();
  }

#pragma unroll
  for (int i = 0; i < 4; i++) {
    int rbase = m0 + wm * 64 + i * 16 + q * 4;
#pragma unroll
    for (int j = 0; j < 4; j++) {
      int colg = n0 + wn * 64 + j * 16 + lrow;
      if (colg < N) {
        float bv = bias[colg];
#pragma unroll
        for (int rg = 0; rg < 4; rg++) {
          int rowg = rbase + rg;
          if (rowg < M) C[(long)rowg * ldc + colg] = acc[i][j][rg] + bv;
        }
      }
    }
  }
}

// ---------------- attention: scores + softmax + weighted + gate (coalesced) --------
__global__ __launch_bounds__(256) void k_attn(
    const float* __restrict__ e1, const float* __restrict__ e2,
    const float* __restrict__ enc, const float* __restrict__ x4f,
    const int* __restrict__ sou, const float* __restrict__ vw,
    const float* __restrict__ g1w, const float* __restrict__ g1b,
    const float* __restrict__ g2w, const float* __restrict__ g2b,
    const float* __restrict__ g3b, const float* __restrict__ g3dot,
    float* __restrict__ all_out, float* __restrict__ gate,
    float* __restrict__ atten_out)
{
  int r = blockIdx.x;  // b*50+t
  int b = r / 50;
  int tid = threadIdx.x;
  int wv = tid >> 6, lane = tid & 63;
  __shared__ float e2s[512], decs[512], at[256], red[256];
  for (int k = tid; k < 512; k += 256) {
    e2s[k] = e2[(long)r * 512 + k];
    decs[k] = x4f[(long)r * 512 + k];
  }
  __syncthreads();

  // scores: one wave per source row s (coalesced e1 row reads + shuffle reduce)
  for (int s = wv; s < 256; s += 4) {
    const float* row = e1 + ((long)b * 256 + s) * 512;
    float acc = 0.f;
#pragma unroll
    for (int c = 0; c < 8; c++) {
      int h = c * 64 + lane;
      acc += vw[h] * tanhf(row[h] + e2s[h]);
    }
#pragma unroll
    for (int o = 32; o > 0; o >>= 1) acc += __shfl_xor(acc, o);
    if (lane == 0) at[s] = acc;
  }
  __syncthreads();

  float sc = at[tid];
  if (sou[b * 256 + tid] == 0) sc = -INFINITY;
  red[tid] = sc; __syncthreads();
  for (int o = 128; o > 0; o >>= 1) { if (tid < o) red[tid] = fmaxf(red[tid], red[tid + o]); __syncthreads(); }
  float mx = red[0]; __syncthreads();
  float p = expf(sc - mx);
  red[tid] = p; __syncthreads();
  for (int o = 128; o > 0; o >>= 1) { if (tid < o) red[tid] += red[tid + o]; __syncthreads(); }
  float S = red[0]; __syncthreads();
  float a = p / S;
  at[tid] = a;
  atten_out[(long)r * 256 + tid] = a;
  __syncthreads();

  // weighted sum: thread owns h0=tid, h1=tid+256; coalesced enc row reads
  float acc0 = 0.f, acc1 = 0.f;
  const float* eb = enc + (long)b * 256 * 512;
  for (int s = 0; s < 256; s++) {
    float a_s = at[s];
    acc0 += a_s * eb[(long)s * 512 + tid];
    acc1 += a_s * eb[(long)s * 512 + tid + 256];
  }
  all_out[(long)r * 1024 + tid] = acc0;
  all_out[(long)r * 1024 + tid + 256] = acc1;
  all_out[(long)r * 1024 + 512 + tid] = decs[tid];
  all_out[(long)r * 1024 + 512 + tid + 256] = decs[tid + 256];
  float pg = acc0 * g1w[tid] + acc1 * g1w[tid + 256]
           + decs[tid] * g2w[tid] + decs[tid + 256] * g2w[tid + 256];
  red[tid] = pg; __syncthreads();
  for (int o = 128; o > 0; o >>= 1) { if (tid < o) red[tid] += red[tid + o]; __syncthreads(); }
  if (tid == 0) {
    float z = red[0] + g1b[0] + g2b[0] + g3dot[r] + g3b[0];
    gate[r] = 1.f / (1.f + expf(-z));
  }
}

// ------- masked softmax * (1-gate) over logits (online 2-pass) + fused copy scatter -
__global__ __launch_bounds__(1024) void k_softmax(float* __restrict__ out,
                                                  const float* __restrict__ gate,
                                                  const int* __restrict__ ext,
                                                  const float* __restrict__ atten,
                                                  const int* __restrict__ sou) {
  int r = blockIdx.x;
  int b = r / 50;
  int tid = threadIdx.x;
  int nv = VOCAB + ext[b];
  __shared__ float redm[1024];
  __shared__ float reds[1024];
  float* row = out + (long)r * VEXT;
  // online (max, sum) in one pass; nv >= 50000 so every thread sees >= 48 elements
  float m = -INFINITY, s = 0.f;
  for (int c = tid; c < nv; c += 1024) {
    float v = row[c];
    if (v > m) { s = s * expf(m - v) + 1.f; m = v; }
    else s += expf(v - m);
  }
  redm[tid] = m; reds[tid] = s; __syncthreads();
  for (int o = 512; o > 0; o >>= 1) {
    if (tid < o) {
      float m1 = redm[tid], s1 = reds[tid], m2 = redm[tid + o], s2 = reds[tid + o];
      float M = fmaxf(m1, m2);
      redm[tid] = M;
      reds[tid] = s1 * expf(m1 - M) + s2 * expf(m2 - M);
    }
    __syncthreads();
  }
  float M = redm[0];
  float inv = (1.f - gate[r]) / reds[0];
  for (int c = tid; c < VEXT; c += 1024) {
    float v = (c < nv) ? expf(row[c] - M) * inv : 0.f;
    row[c] = v;
  }
  __syncthreads();
  // fused copy-mechanism scatter (row is block-local; all writes above done)
  if (tid < 256) {
    float v = gate[r] * atten[(long)r * 256 + tid];
    atomicAdd(row + sou[b * 256 + tid], v);
  }
}

extern "C" void kernel_launch(void* const* d_in, const int* in_sizes, int n_in,
                              void* d_out, int out_size, void* d_ws, size_t ws_size,
                              hipStream_t stream) {
  (void)in_sizes; (void)n_in; (void)out_size;
  const int* sou = (const int*)d_in[0];
  const int* tar = (const int*)d_in[1];
  const float* hidden = (const float*)d_in[2];
  const float* enc = (const float*)d_in[3];
  const int* ext = (const int*)d_in[4];
  const float* emb = (const float*)d_in[5];
  const float* wih = (const float*)d_in[6];
  const float* whh = (const float*)d_in[7];
  const float* bih = (const float*)d_in[8];
  const float* bhh = (const float*)d_in[9];
  const float* fc_enc_w = (const float*)d_in[10];
  const float* fc_enc_b = (const float*)d_in[11];
  const float* fc_dec_w = (const float*)d_in[12];
  const float* fc_dec_b = (const float*)d_in[13];
  const float* v_w = (const float*)d_in[14];
  const float* w1 = (const float*)d_in[15];
  const float* b1 = (const float*)d_in[16];
  const float* w2 = (const float*)d_in[17];
  const float* b2 = (const float*)d_in[18];
  const float* g1w = (const float*)d_in[19];
  const float* g1b = (const float*)d_in[20];
  const float* g2w = (const float*)d_in[21];
  const float* g2b = (const float*)d_in[22];
  const float* g3w = (const float*)d_in[23];
  const float* g3b = (const float*)d_in[24];
  float* out = (float*)d_out;

  char* base = (char*)d_ws;
  size_t cur = 0;
  auto alloc = [&](size_t bytes) -> void* {
    void* r = base + cur;
    cur = (cur + bytes + 255) & ~(size_t)255;
    return r;
  };
  u16* wihB = (u16*)alloc(6291456);     // [4][1536][512] bf16
  u16* whhB = (u16*)alloc(6291456);
  u16* w1B  = (u16*)alloc(51511296);    // [50304][512] bf16 (padded)
  u16* encB = (u16*)alloc(2097152);     // [2048][512]
  u16* fceB = (u16*)alloc(524288);      // [512][512]
  u16* fcdB = (u16*)alloc(524288);
  u16* fo2B = (u16*)alloc(1048576);     // [512][1024]
  u16* midB = (u16*)alloc(524288);      // [512][512] (400 real)
  u16* decB = (u16*)alloc(524288);
  u16* allB = (u16*)alloc(1048576);     // [512][1024]
  u16* xB   = (u16*)alloc(3276800);     // [4][16][50][512] bf16
  u16* h0B  = (u16*)alloc(65536);       // [4][16][512]
  u32* hX   = (u32*)alloc(131072);      // [4][2][16][256] u32 (bf16 col-pairs)
  float* x4f = (float*)alloc(819200);   // [400][512]
  float* e1 = (float*)alloc(4194304);   // [2048][512]
  float* e2 = (float*)alloc(819200);    // [400][512]
  float* allo = (float*)alloc(1638400); // [400][1024]
  float* mid = (float*)alloc(819200);   // [400][512]
  float* g3dot = (float*)alloc(1600);
  float* gate = (float*)alloc(1600);
  int* lens = (int*)alloc(32);
  u32* cnt = (u32*)alloc(1024);         // [4][4][16] u32: 4 group-counters/layer
  if (cur > ws_size) return;  // ws too small -> loud failure, recognizable vs stub

  hipMemsetAsync(cnt, 0, 1024, stream);

  // weight / input conversions to bf16 (w1 is folded into k_gru)
  k_conv<<<12288, 256, 0, stream>>>(wih, wihB, 3145728L, 3145728L);
  k_conv<<<12288, 256, 0, stream>>>(whh, whhB, 3145728L, 3145728L);
  k_conv<<<4096, 256, 0, stream>>>(enc, encB, 1048576L, 1048576L);
  k_conv<<<1024, 256, 0, stream>>>(fc_enc_w, fceB, 262144L, 262144L);
  k_conv<<<1024, 256, 0, stream>>>(fc_dec_w, fcdB, 262144L, 262144L);
  k_conv<<<2048, 256, 0, stream>>>(w2, fo2B, 524288L, 524288L);
  k_h0b<<<128, 256, 0, stream>>>(hidden, h0B);
  k_prep<<<400, 256, 0, stream>>>(tar, emb, g3w, xB, g3dot);
  k_lengths<<<1, 64, 0, stream>>>(tar, lens);

  // pipelined GRU (4 layers, split-counter sync) + overlapped w1 conversion
  k_gru<<<256, 128, 0, stream>>>(wihB, whhB, bih, bhh, hidden, h0B, xB, hX, x4f, cnt,
                                 w1, w1B);
  k_mask<<<400, 256, 0, stream>>>(x4f, lens);
  k_conv<<<1024, 256, 0, stream>>>(x4f, decB, 204800L, 262144L);

  // attention path
  k_gemm_bf16<<<dim3(4, 16), 256, 0, stream>>>(encB, fceB, fc_enc_b, e1, 2048, 512, 512, 512);
  k_gemm_bf16<<<dim3(4, 4), 256, 0, stream>>>(decB, fcdB, fc_dec_b, e2, 400, 512, 512, 512);
  k_attn<<<400, 256, 0, stream>>>(e1, e2, enc, x4f, sou, v_w, g1w, g1b, g2w, g2b, g3b,
                                  g3dot, allo, gate, out + OUT_AT_OFF);
  k_conv<<<2048, 256, 0, stream>>>(allo, allB, 409600L, 524288L);
  k_gemm_bf16<<<dim3(4, 4), 256, 0, stream>>>(allB, fo2B, b2, mid, 400, 512, 1024, 512);
  k_conv<<<1024, 256, 0, stream>>>(mid, midB, 204800L, 262144L);

  // logits -> fused masked softmax + copy scatter
  k_gemm_bf16<<<dim3(393, 4), 256, 0, stream>>>(midB, w1B, b1, out, 400, 50256, 512, 50256);
  k_softmax<<<400, 1024, 0, stream>>>(out, gate, ext, out + OUT_AT_OFF, sou);
}

// Round 8
// 999.579 us; speedup vs baseline: 1.1752x; 1.0387x over previous
//
#include <hip/hip_runtime.h>

typedef unsigned short u16;
typedef unsigned int u32;
typedef unsigned long long u64;

using bf16x8 = __attribute__((ext_vector_type(8))) short;
using f32x4  = __attribute__((ext_vector_type(4))) float;
using u32x4  = __attribute__((ext_vector_type(4))) unsigned int;

#define VOCAB 50000
#define VEXT  50256
#define OUT_AT_OFF 20102400L  // 400*50256

__device__ __forceinline__ u16 f2b(float f) {
  u32 x = __float_as_uint(f);
  u32 r = (x + 0x7fffu + ((x >> 16) & 1u)) >> 16;  // RNE f32->bf16
  return (u16)r;
}

// system-scope (MALL-coherent, cache-bypass) helpers: fence-free protocol
__device__ __forceinline__ u32 sload32(const u32* p) {
  return __hip_atomic_load(p, __ATOMIC_RELAXED, __HIP_MEMORY_SCOPE_SYSTEM);
}
__device__ __forceinline__ void sstore64(u64* p, u64 v) {
  __hip_atomic_store(p, v, __ATOMIC_RELAXED, __HIP_MEMORY_SCOPE_SYSTEM);
}
// 16 x dwordx4 system-coherent loads of one 1024B row slice + single waitcnt.
// All loads + the waitcnt live in ONE asm block -> any use of the outputs is
// ordered after the waitcnt; early-clobber outputs avoid addr-pair overlap.
__device__ __forceinline__ void sysload_row(u64 base, u32x4 (&o)[16]) {
  asm volatile(
      "global_load_dwordx4 %0, %16, off sc0 sc1\n\t"
      "global_load_dwordx4 %1, %16, off offset:64 sc0 sc1\n\t"
      "global_load_dwordx4 %2, %16, off offset:128 sc0 sc1\n\t"
      "global_load_dwordx4 %3, %16, off offset:192 sc0 sc1\n\t"
      "global_load_dwordx4 %4, %16, off offset:256 sc0 sc1\n\t"
      "global_load_dwordx4 %5, %16, off offset:320 sc0 sc1\n\t"
      "global_load_dwordx4 %6, %16, off offset:384 sc0 sc1\n\t"
      "global_load_dwordx4 %7, %16, off offset:448 sc0 sc1\n\t"
      "global_load_dwordx4 %8, %16, off offset:512 sc0 sc1\n\t"
      "global_load_dwordx4 %9, %16, off offset:576 sc0 sc1\n\t"
      "global_load_dwordx4 %10, %16, off offset:640 sc0 sc1\n\t"
      "global_load_dwordx4 %11, %16, off offset:704 sc0 sc1\n\t"
      "global_load_dwordx4 %12, %16, off offset:768 sc0 sc1\n\t"
      "global_load_dwordx4 %13, %16, off offset:832 sc0 sc1\n\t"
      "global_load_dwordx4 %14, %16, off offset:896 sc0 sc1\n\t"
      "global_load_dwordx4 %15, %16, off offset:960 sc0 sc1\n\t"
      "s_waitcnt vmcnt(0)"
      : "=&v"(o[0]), "=&v"(o[1]), "=&v"(o[2]), "=&v"(o[3]),
        "=&v"(o[4]), "=&v"(o[5]), "=&v"(o[6]), "=&v"(o[7]),
        "=&v"(o[8]), "=&v"(o[9]), "=&v"(o[10]), "=&v"(o[11]),
        "=&v"(o[12]), "=&v"(o[13]), "=&v"(o[14]), "=&v"(o[15])
      : "v"(base));
}
// 4-way split counters: lanes poll 4 lines (lane&3), 4 transactions/wave/iter
__device__ __forceinline__ void wait_cnt4(const u32* c4, u32 tgt) {
  const u32* p = c4 + (threadIdx.x & 3) * 16;
  unsigned it = 0;
  while (true) {
    u32 v = sload32(p);
    if (__all((int)(v >= tgt))) break;
    __builtin_amdgcn_s_sleep(2);
    if (++it > (1u << 20)) break;  // safety: wrong-but-terminating on logic bug
  }
  asm volatile("" ::: "memory");  // compiler-only barrier (no cache op)
}

// ---------------- generic f32 -> bf16 (with zero row padding at tail) ----------------
__global__ void k_conv(const float* __restrict__ src, u16* __restrict__ dst,
                       long realN, long totalN) {
  long i = (long)blockIdx.x * 256 + threadIdx.x;
  if (i >= totalN) return;
  float v = (i < realN) ? src[i] : 0.f;
  dst[i] = f2b(v);
}

// ---------------- h0 f32 [4][8][512] -> bf16 [4][16][512] (batch-padded) -------------
__global__ void k_h0b(const float* __restrict__ hidden, u16* __restrict__ h0B) {
  int i = blockIdx.x * 256 + threadIdx.x;  // < 4*16*512
  int l = i >> 13, rem = i & 8191, rr = rem >> 9, k = rem & 511;
  float v = (rr < 8) ? hidden[((long)l * 8 + rr) * 512 + k] : 0.f;
  h0B[i] = f2b(v);
}

// ---------------- embedding + g3 dot ----------------
__global__ __launch_bounds__(256) void k_prep(const int* __restrict__ tar,
                                              const float* __restrict__ emb,
                                              const float* __restrict__ g3w,
                                              u16* __restrict__ xB0,
                                              float* __restrict__ g3dot) {
  int r = blockIdx.x;  // b*50+t
  int tid = threadIdx.x;
  int idx = tar[r];
  __shared__ float red[256];
  float p = 0.f;
  for (int k = tid; k < 512; k += 256) {
    float v = (idx == 0) ? 0.f : emb[(long)idx * 512 + k];
    xB0[(long)r * 512 + k] = f2b(v);
    p += v * g3w[k];
  }
  red[tid] = p; __syncthreads();
  for (int o = 128; o > 0; o >>= 1) { if (tid < o) red[tid] += red[tid + o]; __syncthreads(); }
  if (tid == 0) g3dot[r] = red[0];
}

__global__ void k_lengths(const int* __restrict__ tar, int* __restrict__ lens) {
  int b = threadIdx.x;
  if (b < 8) {
    int c = 0;
    for (int t = 0; t < 50; t++) c += (tar[b * 50 + t] > 0) ? 1 : 0;
    lens[b] = (c > 0) ? c : 1;
  }
}

__global__ __launch_bounds__(256) void k_mask(float* __restrict__ x4f,
                                              const int* __restrict__ lens) {
  int r = blockIdx.x, b = r / 50, t = r % 50;
  if (t >= lens[b])
    for (int k = threadIdx.x; k < 512; k += 256) x4f[(long)r * 512 + k] = 0.f;
}

// ---------------- pipelined 4-layer GRU, bf16 MFMA ----------------------------------
// Sync protocol (v7 = v6 counters + wide coherent data path):
//  - per layer, 4 group-counters (8 WGs each); producer: 1 relaxed system atomicAdd
//    per step after an s_waitcnt vmcnt(0) drain. Consumers poll 4 lines.
//  - cross-WG h/x data: producer packs 4 cols/u64 (2 shfl_xor) + relaxed system u64
//    stores; consumer reads 16B chunks via global_load_dwordx4 sc0 sc1 (inline asm,
//    4x fewer MALL transactions than u64 atomics) and ONLY rows 0..7 (batch rows
//    8..15 are padding -> fragments zeroed in-register, halving transactions again).
//  - no wbl2/buffer_inv anywhere: L1/L2 stay hot for the weight streams.
//  - WGs 128..255 convert w1 f32->bf16 (grid-stride) under the latency-bound GRU.
__global__ __launch_bounds__(128, 1) void k_gru(
    const u16* __restrict__ wihB, const u16* __restrict__ whhB,
    const float* __restrict__ bih, const float* __restrict__ bhh,
    const float* __restrict__ hidden, const u16* __restrict__ h0B,
    const u16* __restrict__ xB0, // [8][50][512] bf16 layer-0 input (cached)
    u16* __restrict__ hX,    // [4][2][8][512] bf16 (system, parity dbuf)
    u16* __restrict__ xT,    // [3][8][50][512] bf16 (system, inter-layer handoff)
    float* __restrict__ x4f, // [8][50][512] f32 (layer-3 output, plain stores)
    u32* __restrict__ cnt,   // [4][4][16] u32: 4 group-counters per layer
    const float* __restrict__ w1src, u16* __restrict__ w1B)
{
  const int wg = blockIdx.x;          // 0..255
  const int tid = threadIdx.x;

  if (wg >= 128) {
    // ---- folded w1 conversion: [50304][512] bf16, zero-padded past 25731072 ----
    long tidg = (long)(wg - 128) * 128 + tid;  // 0..16383
    const float4* src4 = (const float4*)w1src;
#pragma unroll 4
    for (int it = 0; it < 393; it++) {
      long e = tidg * 4 + (long)it * 65536;    // quad-aligned element index
      float4 v = {0.f, 0.f, 0.f, 0.f};
      if (e < 25731072L) v = src4[e >> 2];
      u64 o = (u64)f2b(v.x) | ((u64)f2b(v.y) << 16) |
              ((u64)f2b(v.z) << 32) | ((u64)f2b(v.w) << 48);
      *(u64*)(w1B + e) = o;
    }
    return;
  }

  const int l = wg >> 5;              // layer
  const int wg32 = wg & 31;
  const int c0 = wg32 << 4;           // 16-col block of hidden dim
  const int wv = tid >> 6;            // 0: gi wave, 1: gh wave
  const int lane = tid & 63;
  const int lrow = lane & 15;
  const int q = lane >> 4;

  __shared__ float giX[2][3][16][16];  // double-buffered by t&1

  // B fragments: 3 gate tiles x 16 k-steps, re-read per step (L1/L2-hot, no inv)
  const u16* Wsrc = (wv == 0 ? wihB : whhB) + (long)l * 1536 * 512;

  const int col = c0 + lrow;
  const float bir = bih[l * 1536 + col],         bhr = bhh[l * 1536 + col];
  const float biz = bih[l * 1536 + 512 + col],   bhz = bhh[l * 1536 + 512 + col];
  const float bin_ = bih[l * 1536 + 1024 + col], bhn = bhh[l * 1536 + 1024 + col];

  // hprev carried in registers: same lane owns (bb=q*4+rg, col) every step
  float hreg[4];
  if (wv == 1) {
#pragma unroll
    for (int rg = 0; rg < 4; rg++) {
      int bb = q * 4 + rg;
      hreg[rg] = (bb < 8) ? hidden[((long)l * 8 + bb) * 512 + col] : 0.f;
    }
  }

  for (int t = 0; t < 50; t++) {
    bf16x8 af[16];
    if (wv == 0) {
      if (l > 0) {
        wait_cnt4(cnt + (l - 1) * 64, 8u * (u32)(t + 1));  // layer l-1 finished step t
        if (lrow < 8) {
          u32x4 o[16];
          sysload_row((u64)(xT + (((long)(l - 1) * 8 + lrow) * 50 + t) * 512 + q * 8), o);
#pragma unroll
          for (int ks = 0; ks < 16; ks++) { union { u32x4 u; bf16x8 b; } c; c.u = o[ks]; af[ks] = c.b; }
        } else {
#pragma unroll
          for (int ks = 0; ks < 16; ks++) af[ks] = bf16x8{0, 0, 0, 0, 0, 0, 0, 0};
        }
      } else {
        if (lrow < 8) {
          const u16* Asrc = xB0 + ((long)lrow * 50 + t) * 512;
#pragma unroll
          for (int ks = 0; ks < 16; ks++) af[ks] = *(const bf16x8*)(Asrc + ks * 32 + q * 8);
        } else {
#pragma unroll
          for (int ks = 0; ks < 16; ks++) af[ks] = bf16x8{0, 0, 0, 0, 0, 0, 0, 0};
        }
      }
    } else {
      if (t > 0) {
        wait_cnt4(cnt + l * 64, 8u * (u32)t);              // own layer finished step t-1
        if (lrow < 8) {
          u32x4 o[16];
          sysload_row((u64)(hX + (((long)l * 2 + ((t - 1) & 1)) * 8 + lrow) * 512 + q * 8), o);
#pragma unroll
          for (int ks = 0; ks < 16; ks++) { union { u32x4 u; bf16x8 b; } c; c.u = o[ks]; af[ks] = c.b; }
        } else {
#pragma unroll
          for (int ks = 0; ks < 16; ks++) af[ks] = bf16x8{0, 0, 0, 0, 0, 0, 0, 0};
        }
      } else {
        const u16* Asrc = h0B + ((long)l * 16 + lrow) * 512;  // rows 8-15 zeroed
#pragma unroll
        for (int ks = 0; ks < 16; ks++) af[ks] = *(const bf16x8*)(Asrc + ks * 32 + q * 8);
      }
    }

    f32x4 a0 = {0.f, 0.f, 0.f, 0.f}, a1 = {0.f, 0.f, 0.f, 0.f}, a2 = {0.f, 0.f, 0.f, 0.f};
#pragma unroll
    for (int ks = 0; ks < 16; ks++) {
      bf16x8 b0 = *(const bf16x8*)(Wsrc + (long)(0 * 512 + c0 + lrow) * 512 + ks * 32 + q * 8);
      bf16x8 b1 = *(const bf16x8*)(Wsrc + (long)(1 * 512 + c0 + lrow) * 512 + ks * 32 + q * 8);
      bf16x8 b2 = *(const bf16x8*)(Wsrc + (long)(2 * 512 + c0 + lrow) * 512 + ks * 32 + q * 8);
      a0 = __builtin_amdgcn_mfma_f32_16x16x32_bf16(af[ks], b0, a0, 0, 0, 0);
      a1 = __builtin_amdgcn_mfma_f32_16x16x32_bf16(af[ks], b1, a1, 0, 0, 0);
      a2 = __builtin_amdgcn_mfma_f32_16x16x32_bf16(af[ks], b2, a2, 0, 0, 0);
    }

    if (wv == 0) {
#pragma unroll
      for (int rg = 0; rg < 4; rg++) {
        giX[t & 1][0][q * 4 + rg][lrow] = a0[rg];
        giX[t & 1][1][q * 4 + rg][lrow] = a1[rg];
        giX[t & 1][2][q * 4 + rg][lrow] = a2[rg];
      }
    }
    __syncthreads();

    if (wv == 1) {
#pragma unroll
      for (int rg = 0; rg < 4; rg++) {
        int bb = q * 4 + rg;
        float hnew = 0.f;
        u16 hb16 = 0;
        if (bb < 8) {
          float gir = giX[t & 1][0][bb][lrow] + bir;
          float giz = giX[t & 1][1][bb][lrow] + biz;
          float gin = giX[t & 1][2][bb][lrow] + bin_;
          float ghr = a0[rg] + bhr;
          float ghz = a1[rg] + bhz;
          float ghn = a2[rg] + bhn;
          float hprev = hreg[rg];
          float rr = 1.f / (1.f + expf(-(gir + ghr)));
          float zz = 1.f / (1.f + expf(-(giz + ghz)));
          float nn = tanhf(gin + rr * ghn);
          hnew = (1.f - zz) * nn + zz * hprev;
          hreg[rg] = hnew;
          hb16 = f2b(hnew);
        }
        // pack 4 consecutive cols into one u64 (2 shfl_xor rounds, wave-uniform)
        u32 p32 = (u32)hb16 | ((u32)(u16)__shfl_xor((int)hb16, 1) << 16);
        u64 p64 = (u64)p32 | ((u64)(u32)__shfl_xor((int)p32, 2) << 32);
        if (bb < 8) {
          if ((lrow & 3) == 0) {
            long hrow = ((long)l * 2 + (t & 1)) * 8 + bb;
            sstore64((u64*)hX + hrow * 64 + (col >> 3) * 2 + ((col >> 2) & 1), p64);
            if (l < 3)
              sstore64((u64*)xT + ((((long)l * 8 + bb) * 50 + t) * 64) + (col >> 2), p64);
          }
          if (l == 3) x4f[((long)bb * 50 + t) * 512 + col] = hnew;
        }
      }
      // release: drain this wave's stores to the coherence point, then publish
      asm volatile("s_waitcnt vmcnt(0)" ::: "memory");
      if (lane == 0)
        __hip_atomic_fetch_add(cnt + (long)l * 64 + (wg32 >> 3) * 16, 1u,
                               __ATOMIC_RELAXED, __HIP_MEMORY_SCOPE_SYSTEM);
    }
  }
}

// ---------------- generic bf16 MFMA GEMM: C[M,N] = A[Mp,K] @ Bm[Np,K]^T + bias ------
__global__ __launch_bounds__(256, 2) void k_gemm_bf16(
    const u16* __restrict__ A, const u16* __restrict__ Bm,
    const float* __restrict__ bias, float* __restrict__ C,
    int M, int N, int K, int ldc)
{
  __shared__ __align__(16) u16 As[4096];
  __shared__ __align__(16) u16 Bs[4096];
  const int tid = threadIdx.x;
  const int wv = tid >> 6, lane = tid & 63;
  const int wm = wv >> 1, wn = wv & 1;
  const int lrow = lane & 15, q = lane >> 4;
  const int m0 = blockIdx.y * 128, n0 = blockIdx.x * 128;

  f32x4 acc[4][4];
#pragma unroll
  for (int i = 0; i < 4; i++)
#pragma unroll
    for (int j = 0; j < 4; j++) acc[i][j] = {0.f, 0.f, 0.f, 0.f};

  for (int k0 = 0; k0 < K; k0 += 32) {
#pragma unroll
    for (int i = 0; i < 2; i++) {
      int c = i * 256 + tid;
      int row = c >> 2, ko = (c & 3) << 3;
      *(uint4*)(As + c * 8) = *(const uint4*)(A + (long)(m0 + row) * K + k0 + ko);
      *(uint4*)(Bs + c * 8) = *(const uint4*)(Bm + (long)(n0 + row) * K + k0 + ko);
    }
    __syncthreads();
    bf16x8 af[4], bfr[4];
#pragma unroll
    for (int i = 0; i < 4; i++) af[i] = *(const bf16x8*)(As + (wm * 64 + i * 16 + lrow) * 32 + q * 8);
#pragma unroll
    for (int j = 0; j < 4; j++) bfr[j] = *(const bf16x8*)(Bs + (wn * 64 + j * 16 + lrow) * 32 + q * 8);
#pragma unroll
    for (int i = 0; i < 4; i++)
#pragma unroll
      for (int j = 0; j < 4; j++)
        acc[i][j] = __builtin_amdgcn_mfma_f32_16x16x32_bf16(af[i], bfr[j], acc[i][j], 0, 0, 0);
    __syncthreads();
  }

#pragma unroll
  for (int i = 0; i < 4; i++) {
    int rbase = m0 + wm * 64 + i * 16 + q * 4;
#pragma unroll
    for (int j = 0; j < 4; j++) {
      int colg = n0 + wn * 64 + j * 16 + lrow;
      if (colg < N) {
        float bv = bias[colg];
#pragma unroll
        for (int rg = 0; rg < 4; rg++) {
          int rowg = rbase + rg;
          if (rowg < M) C[(long)rowg * ldc + colg] = acc[i][j][rg] + bv;
        }
      }
    }
  }
}

// ---------------- attention: scores + softmax + weighted + gate (coalesced) --------
__global__ __launch_bounds__(256) void k_attn(
    const float* __restrict__ e1, const float* __restrict__ e2,
    const float* __restrict__ enc, const float* __restrict__ x4f,
    const int* __restrict__ sou, const float* __restrict__ vw,
    const float* __restrict__ g1w, const float* __restrict__ g1b,
    const float* __restrict__ g2w, const float* __restrict__ g2b,
    const float* __restrict__ g3b, const float* __restrict__ g3dot,
    float* __restrict__ all_out, float* __restrict__ gate,
    float* __restrict__ atten_out)
{
  int r = blockIdx.x;  // b*50+t
  int b = r / 50;
  int tid = threadIdx.x;
  int wv = tid >> 6, lane = tid & 63;
  __shared__ float e2s[512], decs[512], at[256], red[256];
  for (int k = tid; k < 512; k += 256) {
    e2s[k] = e2[(long)r * 512 + k];
    decs[k] = x4f[(long)r * 512 + k];
  }
  __syncthreads();

  // scores: one wave per source row s (coalesced e1 row reads + shuffle reduce)
  for (int s = wv; s < 256; s += 4) {
    const float* row = e1 + ((long)b * 256 + s) * 512;
    float acc = 0.f;
#pragma unroll
    for (int c = 0; c < 8; c++) {
      int h = c * 64 + lane;
      acc += vw[h] * tanhf(row[h] + e2s[h]);
    }
#pragma unroll
    for (int o = 32; o > 0; o >>= 1) acc += __shfl_xor(acc, o);
    if (lane == 0) at[s] = acc;
  }
  __syncthreads();

  float sc = at[tid];
  if (sou[b * 256 + tid] == 0) sc = -INFINITY;
  red[tid] = sc; __syncthreads();
  for (int o = 128; o > 0; o >>= 1) { if (tid < o) red[tid] = fmaxf(red[tid], red[tid + o]); __syncthreads(); }
  float mx = red[0]; __syncthreads();
  float p = expf(sc - mx);
  red[tid] = p; __syncthreads();
  for (int o = 128; o > 0; o >>= 1) { if (tid < o) red[tid] += red[tid + o]; __syncthreads(); }
  float S = red[0]; __syncthreads();
  float a = p / S;
  at[tid] = a;
  atten_out[(long)r * 256 + tid] = a;
  __syncthreads();

  // weighted sum: thread owns h0=tid, h1=tid+256; coalesced enc row reads
  float acc0 = 0.f, acc1 = 0.f;
  const float* eb = enc + (long)b * 256 * 512;
  for (int s = 0; s < 256; s++) {
    float a_s = at[s];
    acc0 += a_s * eb[(long)s * 512 + tid];
    acc1 += a_s * eb[(long)s * 512 + tid + 256];
  }
  all_out[(long)r * 1024 + tid] = acc0;
  all_out[(long)r * 1024 + tid + 256] = acc1;
  all_out[(long)r * 1024 + 512 + tid] = decs[tid];
  all_out[(long)r * 1024 + 512 + tid + 256] = decs[tid + 256];
  float pg = acc0 * g1w[tid] + acc1 * g1w[tid + 256]
           + decs[tid] * g2w[tid] + decs[tid + 256] * g2w[tid + 256];
  red[tid] = pg; __syncthreads();
  for (int o = 128; o > 0; o >>= 1) { if (tid < o) red[tid] += red[tid + o]; __syncthreads(); }
  if (tid == 0) {
    float z = red[0] + g1b[0] + g2b[0] + g3dot[r] + g3b[0];
    gate[r] = 1.f / (1.f + expf(-z));
  }
}

// ------- masked softmax * (1-gate) over logits (online 2-pass) + fused copy scatter -
__global__ __launch_bounds__(1024) void k_softmax(float* __restrict__ out,
                                                  const float* __restrict__ gate,
                                                  const int* __restrict__ ext,
                                                  const float* __restrict__ atten,
                                                  const int* __restrict__ sou) {
  int r = blockIdx.x;
  int b = r / 50;
  int tid = threadIdx.x;
  int nv = VOCAB + ext[b];
  __shared__ float redm[1024];
  __shared__ float reds[1024];
  float* row = out + (long)r * VEXT;
  // online (max, sum) in one pass; nv >= 50000 so every thread sees >= 48 elements
  float m = -INFINITY, s = 0.f;
  for (int c = tid; c < nv; c += 1024) {
    float v = row[c];
    if (v > m) { s = s * expf(m - v) + 1.f; m = v; }
    else s += expf(v - m);
  }
  redm[tid] = m; reds[tid] = s; __syncthreads();
  for (int o = 512; o > 0; o >>= 1) {
    if (tid < o) {
      float m1 = redm[tid], s1 = reds[tid], m2 = redm[tid + o], s2 = reds[tid + o];
      float M = fmaxf(m1, m2);
      redm[tid] = M;
      reds[tid] = s1 * expf(m1 - M) + s2 * expf(m2 - M);
    }
    __syncthreads();
  }
  float M = redm[0];
  float inv = (1.f - gate[r]) / reds[0];
  for (int c = tid; c < VEXT; c += 1024) {
    float v = (c < nv) ? expf(row[c] - M) * inv : 0.f;
    row[c] = v;
  }
  __syncthreads();
  // fused copy-mechanism scatter (row is block-local; all writes above done)
  if (tid < 256) {
    float v = gate[r] * atten[(long)r * 256 + tid];
    atomicAdd(row + sou[b * 256 + tid], v);
  }
}

extern "C" void kernel_launch(void* const* d_in, const int* in_sizes, int n_in,
                              void* d_out, int out_size, void* d_ws, size_t ws_size,
                              hipStream_t stream) {
  (void)in_sizes; (void)n_in; (void)out_size;
  const int* sou = (const int*)d_in[0];
  const int* tar = (const int*)d_in[1];
  const float* hidden = (const float*)d_in[2];
  const float* enc = (const float*)d_in[3];
  const int* ext = (const int*)d_in[4];
  const float* emb = (const float*)d_in[5];
  const float* wih = (const float*)d_in[6];
  const float* whh = (const float*)d_in[7];
  const float* bih = (const float*)d_in[8];
  const float* bhh = (const float*)d_in[9];
  const float* fc_enc_w = (const float*)d_in[10];
  const float* fc_enc_b = (const float*)d_in[11];
  const float* fc_dec_w = (const float*)d_in[12];
  const float* fc_dec_b = (const float*)d_in[13];
  const float* v_w = (const float*)d_in[14];
  const float* w1 = (const float*)d_in[15];
  const float* b1 = (const float*)d_in[16];
  const float* w2 = (const float*)d_in[17];
  const float* b2 = (const float*)d_in[18];
  const float* g1w = (const float*)d_in[19];
  const float* g1b = (const float*)d_in[20];
  const float* g2w = (const float*)d_in[21];
  const float* g2b = (const float*)d_in[22];
  const float* g3w = (const float*)d_in[23];
  const float* g3b = (const float*)d_in[24];
  float* out = (float*)d_out;

  char* base = (char*)d_ws;
  size_t cur = 0;
  auto alloc = [&](size_t bytes) -> void* {
    void* r = base + cur;
    cur = (cur + bytes + 255) & ~(size_t)255;
    return r;
  };
  u16* wihB = (u16*)alloc(6291456);     // [4][1536][512] bf16
  u16* whhB = (u16*)alloc(6291456);
  u16* w1B  = (u16*)alloc(51511296);    // [50304][512] bf16 (padded)
  u16* encB = (u16*)alloc(2097152);     // [2048][512]
  u16* fceB = (u16*)alloc(524288);      // [512][512]
  u16* fcdB = (u16*)alloc(524288);
  u16* fo2B = (u16*)alloc(1048576);     // [512][1024]
  u16* midB = (u16*)alloc(524288);      // [512][512] (400 real)
  u16* decB = (u16*)alloc(524288);
  u16* allB = (u16*)alloc(1048576);     // [512][1024]
  u16* xB0  = (u16*)alloc(819200);      // [8][50][512] bf16 layer-0 input
  u16* h0B  = (u16*)alloc(65536);       // [4][16][512]
  u16* hX   = (u16*)alloc(65536);       // [4][2][8][512] bf16 (system)
  u16* xT   = (u16*)alloc(1228800);     // [3][8][50][512] bf16 (system)
  float* x4f = (float*)alloc(819200);   // [400][512]
  float* e1 = (float*)alloc(4194304);   // [2048][512]
  float* e2 = (float*)alloc(819200);    // [400][512]
  float* allo = (float*)alloc(1638400); // [400][1024]
  float* mid = (float*)alloc(819200);   // [400][512]
  float* g3dot = (float*)alloc(1600);
  float* gate = (float*)alloc(1600);
  int* lens = (int*)alloc(32);
  u32* cnt = (u32*)alloc(1024);         // [4][4][16] u32: 4 group-counters/layer
  if (cur > ws_size) return;  // ws too small -> loud failure, recognizable vs stub

  hipMemsetAsync(cnt, 0, 1024, stream);

  // weight / input conversions to bf16 (w1 is folded into k_gru)
  k_conv<<<12288, 256, 0, stream>>>(wih, wihB, 3145728L, 3145728L);
  k_conv<<<12288, 256, 0, stream>>>(whh, whhB, 3145728L, 3145728L);
  k_conv<<<4096, 256, 0, stream>>>(enc, encB, 1048576L, 1048576L);
  k_conv<<<1024, 256, 0, stream>>>(fc_enc_w, fceB, 262144L, 262144L);
  k_conv<<<1024, 256, 0, stream>>>(fc_dec_w, fcdB, 262144L, 262144L);
  k_conv<<<2048, 256, 0, stream>>>(w2, fo2B, 524288L, 524288L);
  k_h0b<<<128, 256, 0, stream>>>(hidden, h0B);
  k_prep<<<400, 256, 0, stream>>>(tar, emb, g3w, xB0, g3dot);
  k_lengths<<<1, 64, 0, stream>>>(tar, lens);

  // pipelined GRU (4 layers, split-counter sync, wide coherent loads) + w1 conv
  k_gru<<<256, 128, 0, stream>>>(wihB, whhB, bih, bhh, hidden, h0B, xB0, hX, xT, x4f,
                                 cnt, w1, w1B);
  k_mask<<<400, 256, 0, stream>>>(x4f, lens);
  k_conv<<<1024, 256, 0, stream>>>(x4f, decB, 204800L, 262144L);

  // attention path
  k_gemm_bf16<<<dim3(4, 16), 256, 0, stream>>>(encB, fceB, fc_enc_b, e1, 2048, 512, 512, 512);
  k_gemm_bf16<<<dim3(4, 4), 256, 0, stream>>>(decB, fcdB, fc_dec_b, e2, 400, 512, 512, 512);
  k_attn<<<400, 256, 0, stream>>>(e1, e2, enc, x4f, sou, v_w, g1w, g1b, g2w, g2b, g3b,
                                  g3dot, allo, gate, out + OUT_AT_OFF);
  k_conv<<<2048, 256, 0, stream>>>(allo, allB, 409600L, 524288L);
  k_gemm_bf16<<<dim3(4, 4), 256, 0, stream>>>(allB, fo2B, b2, mid, 400, 512, 1024, 512);
  k_conv<<<1024, 256, 0, stream>>>(mid, midB, 204800L, 262144L);

  // logits -> fused masked softmax + copy scatter
  k_gemm_bf16<<<dim3(393, 4), 256, 0, stream>>>(midB, w1B, b1, out, 400, 50256, 512, 50256);
  k_softmax<<<400, 1024, 0, stream>>>(out, gate, ext, out + OUT_AT_OFF, sou);
}